// Round 1
// 1675.246 us; speedup vs baseline: 1.1110x; 1.1110x over previous
//
#include <hip/hip_runtime.h>
#include <hip/hip_bf16.h>
#include <math.h>

typedef __hip_bfloat16 bf16;
typedef __attribute__((ext_vector_type(8))) __bf16 bf16x8;
typedef __attribute__((ext_vector_type(4))) float floatx4;

#define CDIM 192
#define N_WINDOWS 2048
#define ATT_SCALE 0.17677669529663687f   // 1/sqrt(32)

__device__ inline float toF(float v) { return v; }
__device__ inline float toF(bf16 v) { return __bfloat162float(v); }

// windowed (wi, n, col) -> natural flat element index
__device__ inline long nat_index(int wi, int n, int col) {
    int wb = wi & 15, hb = (wi >> 4) & 15, tb = (wi >> 8) & 3, bb = wi >> 10;
    int t  = tb * 2 + (n >> 6);
    int hh = hb * 8 + ((n >> 3) & 7);
    int w  = wb * 8 + (n & 7);
    return ((((long)(bb * 8 + t)) * 128 + hh) * 128 + w) * CDIM + col;
}

// ---------------------------------------------------------------------------
// Weight pre-conversion f32 -> bf16 (once per launch; removes per-block cvt
// work from every GEMM block).  n must be a multiple of 8.
// ---------------------------------------------------------------------------
__launch_bounds__(256)
__global__ void cvt_w_kernel(const float* __restrict__ src, bf16* __restrict__ dst, int n) {
    int i = (blockIdx.x * 256 + threadIdx.x) * 8;
    if (i < n) {
        float4 a = *(const float4*)(src + i);
        float4 b = *(const float4*)(src + i + 4);
        bf16x8 o;
        o[0] = (__bf16)a.x; o[1] = (__bf16)a.y; o[2] = (__bf16)a.z; o[3] = (__bf16)a.w;
        o[4] = (__bf16)b.x; o[5] = (__bf16)b.y; o[6] = (__bf16)b.z; o[7] = (__bf16)b.w;
        *(bf16x8*)(dst + i) = o;
    }
}

// ---------------------------------------------------------------------------
// LayerNorm, one wave per row of 192. WINDOWED: gather from natural-layout x
// (global window wi_base + local), write slab-local windowed rows.
// ---------------------------------------------------------------------------
template<bool WINDOWED, typename T>
__launch_bounds__(256)
__global__ void ln_kernel(const T* __restrict__ x, const float* __restrict__ g,
                          const float* __restrict__ bta, bf16* __restrict__ out,
                          int wi_base) {
    int row = blockIdx.x * 4 + (threadIdx.x >> 6);   // slab-local row
    int lane = threadIdx.x & 63;
    long src;
    if (WINDOWED) {
        src = nat_index(wi_base + (row >> 7), row & 127, 0);
    } else {
        src = (long)row * CDIM;
    }
    float v0 = toF(x[src + lane]);
    float v1 = toF(x[src + lane + 64]);
    float v2 = toF(x[src + lane + 128]);
    float s = v0 + v1 + v2;
    float sq = v0 * v0 + v1 * v1 + v2 * v2;
    #pragma unroll
    for (int o = 32; o > 0; o >>= 1) { s += __shfl_xor(s, o); sq += __shfl_xor(sq, o); }
    float mean = s * (1.0f / 192.0f);
    float var  = sq * (1.0f / 192.0f) - mean * mean;
    float rstd = rsqrtf(fmaxf(var, 0.0f) + 1e-5f);
    long dst = (long)row * CDIM;
    out[dst + lane]       = __float2bfloat16((v0 - mean) * rstd * g[lane]       + bta[lane]);
    out[dst + lane + 64]  = __float2bfloat16((v1 - mean) * rstd * g[lane + 64]  + bta[lane + 64]);
    out[dst + lane + 128] = __float2bfloat16((v2 - mean) * rstd * g[lane + 128] + bta[lane + 128]);
}

// ---------------------------------------------------------------------------
// GEMM: C[M,N] = A[M,K](bf16) @ W[N,K]^T(bf16, pre-converted).
// BM=128, BN=64, BK=32; 256 threads = 4 waves, each wave 32x64 (2x4 mfma).
// ---------------------------------------------------------------------------
template<typename Epi>
__launch_bounds__(256)
__global__ void gemm_bt(const bf16* __restrict__ A, const bf16* __restrict__ Wt,
                        int K, Epi epi) {
    __shared__ __align__(16) bf16 sA[128 * 32];
    __shared__ __align__(16) bf16 sW[64 * 32];
    const int tid = threadIdx.x;
    const int lane = tid & 63;
    const int wv = tid >> 6;
    const int m0 = blockIdx.x * 128;
    const int n0 = blockIdx.y * 64;

    floatx4 acc[2][4] = {};

    for (int k0 = 0; k0 < K; k0 += 32) {
        #pragma unroll
        for (int i = 0; i < 2; ++i) {   // A tile 128x32
            int idx = tid + i * 256;
            int row = idx >> 2, kc = (idx & 3) << 3;
            *(uint4*)(&sA[row * 32 + kc]) =
                *(const uint4*)(A + (long)(m0 + row) * K + k0 + kc);
        }
        {   // W tile 64x32 (bf16, plain vector copy)
            int row = tid >> 2, kc = (tid & 3) << 3;
            *(uint4*)(&sW[row * 32 + kc]) =
                *(const uint4*)(Wt + (long)(n0 + row) * K + k0 + kc);
        }
        __syncthreads();
        bf16x8 aF[2], bF[4];
        #pragma unroll
        for (int rt = 0; rt < 2; ++rt)
            aF[rt] = *(const bf16x8*)(&sA[(wv * 32 + rt * 16 + (lane & 15)) * 32 + (lane >> 4) * 8]);
        #pragma unroll
        for (int ct = 0; ct < 4; ++ct)
            bF[ct] = *(const bf16x8*)(&sW[(ct * 16 + (lane & 15)) * 32 + (lane >> 4) * 8]);
        #pragma unroll
        for (int rt = 0; rt < 2; ++rt)
            #pragma unroll
            for (int ct = 0; ct < 4; ++ct)
                acc[rt][ct] = __builtin_amdgcn_mfma_f32_16x16x32_bf16(aF[rt], bF[ct], acc[rt][ct], 0, 0, 0);
        __syncthreads();
    }
    #pragma unroll
    for (int rt = 0; rt < 2; ++rt)
        #pragma unroll
        for (int ct = 0; ct < 4; ++ct)
            #pragma unroll
            for (int r = 0; r < 4; ++r) {
                int row = m0 + wv * 32 + rt * 16 + (lane >> 4) * 4 + r;
                int col = n0 + ct * 16 + (lane & 15);
                epi(row, col, acc[rt][ct][r]);
            }
}

// ------------------------------ epilogues ----------------------------------
struct EpiQKV {
    const float* bias; bf16 *q, *k, *v;
    __device__ void operator()(int row, int col, float val) const {
        val += bias[col];
        int wi = row >> 7, n = row & 127;          // slab-local window
        int part = col / 192, rem = col - part * 192;
        int h = rem >> 5, d = rem & 31;
        long base = (long)(wi * 6 + h);
        if (part == 0)      q[(base * 128 + n) * 32 + d] = __float2bfloat16(val);
        else if (part == 1) k[(base * 128 + n) * 32 + d] = __float2bfloat16(val);
        else                v[(base * 32 + d) * 128 + n] = __float2bfloat16(val); // transposed
    }
};

struct EpiProj {   // x2(local, windowed) = attn_proj + x(natural, global)
    const float* bias; const float* x; bf16* x2; int wi_base;
    __device__ void operator()(int row, int col, float val) const {
        val += bias[col];
        long nat = nat_index(wi_base + (row >> 7), row & 127, col);
        x2[(long)row * CDIM + col] = __float2bfloat16(val + x[nat]);
    }
};

struct EpiGelu {
    const float* bias; bf16* h1;
    __device__ void operator()(int row, int col, float val) const {
        val += bias[col];
        float g = 0.5f * val * (1.0f + erff(val * 0.70710678118654752f));
        h1[(long)row * 768 + col] = __float2bfloat16(g);
    }
};

struct EpiOut {    // out(natural, global) = fc2 + x2(local, windowed)
    const float* bias; const bf16* x2; float* out; int wi_base;
    __device__ void operator()(int row, int col, float val) const {
        val += bias[col];
        long nat = nat_index(wi_base + (row >> 7), row & 127, col);
        out[nat] = val + __bfloat162float(x2[(long)row * CDIM + col]);
    }
};

// ---------------------------------------------------------------------------
// Attention: one block per (local window, head). QK^T -> softmax -> PV.
// ---------------------------------------------------------------------------
__device__ inline float rel_bias(const float* bt, int h, int n, int m) {
    int tn = n >> 6, hn = (n >> 3) & 7, wn = n & 7;
    int tm = m >> 6, hm = (m >> 3) & 7, wm = m & 7;
    int idx = (tn - tm + 1) * 225 + (hn - hm + 7) * 15 + (wn - wm + 7);
    return bt[idx * 6 + h];
}

__launch_bounds__(256)
__global__ void attn_kernel(const bf16* __restrict__ q, const bf16* __restrict__ k,
                            const bf16* __restrict__ vT, const float* __restrict__ bt,
                            bf16* __restrict__ out) {
    __shared__ __align__(16) bf16 sQ[128 * 32];
    __shared__ __align__(16) bf16 sK[128 * 32];
    __shared__ __align__(16) bf16 sVT[32 * 128];
    __shared__ __align__(16) bf16 sP[128 * 128];
    const int blk = blockIdx.x;           // wi_local*6 + h
    const int h = blk % 6;
    const int wi = blk / 6;
    const int tid = threadIdx.x, lane = tid & 63, wv = tid >> 6;
    const bf16* qg = q + (long)blk * 4096;
    const bf16* kg = k + (long)blk * 4096;
    const bf16* vg = vT + (long)blk * 4096;
    #pragma unroll
    for (int i = 0; i < 2; ++i) {
        int idx = (tid + i * 256) * 8;
        *(uint4*)(&sQ[idx])  = *(const uint4*)(qg + idx);
        *(uint4*)(&sK[idx])  = *(const uint4*)(kg + idx);
        *(uint4*)(&sVT[idx]) = *(const uint4*)(vg + idx);
    }
    __syncthreads();

    const int mrow = wv * 32;
    const int colb = lane & 15, quad = lane >> 4;
    floatx4 zero = {0.f, 0.f, 0.f, 0.f};
    floatx4 s[2][8];
    bf16x8 aF[2];
    #pragma unroll
    for (int rt = 0; rt < 2; ++rt)
        aF[rt] = *(const bf16x8*)(&sQ[(mrow + rt * 16 + colb) * 32 + quad * 8]);
    #pragma unroll
    for (int ct = 0; ct < 8; ++ct) {
        bf16x8 bF = *(const bf16x8*)(&sK[(ct * 16 + colb) * 32 + quad * 8]);
        #pragma unroll
        for (int rt = 0; rt < 2; ++rt)
            s[rt][ct] = __builtin_amdgcn_mfma_f32_16x16x32_bf16(aF[rt], bF, zero, 0, 0, 0);
    }
    #pragma unroll
    for (int rt = 0; rt < 2; ++rt) {
        #pragma unroll
        for (int r = 0; r < 4; ++r) {
            int n = mrow + rt * 16 + quad * 4 + r;
            float vals[8];
            float mx = -1e30f;
            #pragma unroll
            for (int ct = 0; ct < 8; ++ct) {
                float v = s[rt][ct][r] * ATT_SCALE + rel_bias(bt, h, n, ct * 16 + colb);
                vals[ct] = v; mx = fmaxf(mx, v);
            }
            #pragma unroll
            for (int o = 1; o < 16; o <<= 1) mx = fmaxf(mx, __shfl_xor(mx, o));
            float sum = 0.f;
            #pragma unroll
            for (int ct = 0; ct < 8; ++ct) { vals[ct] = __expf(vals[ct] - mx); sum += vals[ct]; }
            #pragma unroll
            for (int o = 1; o < 16; o <<= 1) sum += __shfl_xor(sum, o);
            float inv = 1.0f / sum;
            #pragma unroll
            for (int ct = 0; ct < 8; ++ct)
                sP[n * 128 + ct * 16 + colb] = __float2bfloat16(vals[ct] * inv);
        }
    }
    __syncthreads();
    floatx4 o[2][2] = {};
    #pragma unroll
    for (int kk = 0; kk < 4; ++kk) {
        bf16x8 aP[2];
        #pragma unroll
        for (int rt = 0; rt < 2; ++rt)
            aP[rt] = *(const bf16x8*)(&sP[(mrow + rt * 16 + colb) * 128 + kk * 32 + quad * 8]);
        #pragma unroll
        for (int ct = 0; ct < 2; ++ct) {
            bf16x8 bV = *(const bf16x8*)(&sVT[(ct * 16 + colb) * 128 + kk * 32 + quad * 8]);
            #pragma unroll
            for (int rt = 0; rt < 2; ++rt)
                o[rt][ct] = __builtin_amdgcn_mfma_f32_16x16x32_bf16(aP[rt], bV, o[rt][ct], 0, 0, 0);
        }
    }
    #pragma unroll
    for (int rt = 0; rt < 2; ++rt)
        #pragma unroll
        for (int ct = 0; ct < 2; ++ct)
            #pragma unroll
            for (int r = 0; r < 4; ++r) {
                int n = mrow + rt * 16 + quad * 4 + r;
                out[((long)(wi * 128 + n)) * CDIM + h * 32 + ct * 16 + colb] =
                    __float2bfloat16(o[rt][ct][r]);
            }
}

// ---------------------------------------------------------------------------
extern "C" void kernel_launch(void* const* d_in, const int* in_sizes, int n_in,
                              void* d_out, int out_size, void* d_ws, size_t ws_size,
                              hipStream_t stream) {
    const float* x      = (const float*)d_in[0];
    const float* n1g    = (const float*)d_in[1];
    const float* n1b    = (const float*)d_in[2];
    const float* qkv_w  = (const float*)d_in[3];
    const float* qkv_b  = (const float*)d_in[4];
    const float* btab   = (const float*)d_in[5];
    const float* proj_w = (const float*)d_in[6];
    const float* proj_b = (const float*)d_in[7];
    const float* n2g    = (const float*)d_in[8];
    const float* n2b    = (const float*)d_in[9];
    const float* fc1_w  = (const float*)d_in[10];
    const float* fc1_b  = (const float*)d_in[11];
    const float* fc2_w  = (const float*)d_in[12];
    const float* fc2_b  = (const float*)d_in[13];
    float* outp = (float*)d_out;

    char* ws = (char*)d_ws;

    // ---- bf16 weight copies at the front of the workspace -----------------
    const int NQKV = 576 * 192, NPROJ = 192 * 192, NFC1 = 768 * 192, NFC2 = 192 * 768;
    bf16* qkvW = (bf16*)ws;
    bf16* projW = qkvW + NQKV;
    bf16* fc1W = projW + NPROJ;
    bf16* fc2W = fc1W + NFC1;
    const size_t WBYTES = (size_t)(NQKV + NPROJ + NFC1 + NFC2) * 2;  // 884736, 4K-aligned

    cvt_w_kernel<<<NQKV / 2048, 256, 0, stream>>>(qkv_w, qkvW, NQKV);
    cvt_w_kernel<<<NPROJ / 2048, 256, 0, stream>>>(proj_w, projW, NPROJ);
    cvt_w_kernel<<<NFC1 / 2048, 256, 0, stream>>>(fc1_w, fc1W, NFC1);
    cvt_w_kernel<<<NFC2 / 2048, 256, 0, stream>>>(fc2_w, fc2W, NFC2);

    // ---- slab sizing: cap S so ALL intermediates stay L3-resident ---------
    // 6 slots of S*128*192 bf16; S=512 -> 145 MB working set < 256 MB L3.
    const size_t per_win = 6UL * 128 * 192 * 2;   // 294912 B per window
    size_t avail = ws_size > WBYTES ? ws_size - WBYTES : 0;
    int S = 512;
    while (S > 64 && (size_t)S * per_win > avail) S >>= 1;

    char* slots = ws + WBYTES;
    const size_t SLOT = (size_t)S * 128 * CDIM * 2;   // bytes per slot
    bf16* bufA = (bf16*)(slots);               // ln1 out -> attn_out -> xn2
    bf16* qb   = (bf16*)(slots + SLOT);        // q -> x2
    bf16* kb   = (bf16*)(slots + 2 * SLOT);    // k -> h1 (4 slots: 2..5)
    bf16* vb   = (bf16*)(slots + 3 * SLOT);    // v (transposed)
    bf16* x2   = qb;
    bf16* h1   = kb;

    for (int s0 = 0; s0 < N_WINDOWS; s0 += S) {
        ln_kernel<true, float><<<S * 32, 256, 0, stream>>>(x, n1g, n1b, bufA, s0);
        gemm_bt<EpiQKV><<<dim3(S, 9), 256, 0, stream>>>(bufA, qkvW, 192, EpiQKV{qkv_b, qb, kb, vb});
        attn_kernel<<<S * 6, 256, 0, stream>>>(qb, kb, vb, btab, bufA);
        gemm_bt<EpiProj><<<dim3(S, 3), 256, 0, stream>>>(bufA, projW, 192, EpiProj{proj_b, x, x2, s0});
        ln_kernel<false, bf16><<<S * 32, 256, 0, stream>>>(x2, n2g, n2b, bufA, 0);
        gemm_bt<EpiGelu><<<dim3(S, 12), 256, 0, stream>>>(bufA, fc1W, 192, EpiGelu{fc1_b, h1});
        gemm_bt<EpiOut><<<dim3(S, 3), 256, 0, stream>>>(h1, fc2W, 768, EpiOut{fc2_b, x2, outp, s0});
    }
}